// Round 16
// baseline (1975.197 us; speedup 1.0000x reference)
//
#include <hip/hip_runtime.h>

#define NROW 16384
#define DDIM 128

typedef _Float16 f16x8 __attribute__((ext_vector_type(8)));
typedef __fp16 fp16x2 __attribute__((ext_vector_type(2)));
typedef float f32x4 __attribute__((ext_vector_type(4)));

__device__ __forceinline__ unsigned short f2h(float x) {
  union { _Float16 f; unsigned short u; } cvt;
  cvt.f = (_Float16)x;  // RNE
  return cvt.u;
}

__device__ __forceinline__ unsigned pkrtz(float a, float b) {
  union { fp16x2 h; unsigned u; } cvt;
  cvt.h = __builtin_amdgcn_cvt_pkrtz(a, b);
  return cvt.u;
}

__device__ __forceinline__ void block_sync() {
  asm volatile("s_waitcnt lgkmcnt(0)" ::: "memory");
  __builtin_amdgcn_s_barrier();
  asm volatile("" ::: "memory");
}

// ---------------- prep: ht[d][i] = fp16(h[i][d]) ----------------
__global__ __launch_bounds__(256) void prep_ht(const float* __restrict__ h,
                                               unsigned short* __restrict__ ht) {
  __shared__ unsigned short tile[DDIM][65];
  const int t = threadIdx.x;
  const int i0 = blockIdx.x * 64;
#pragma unroll
  for (int rep = 0; rep < 8; ++rep) {
    int idx = rep * 256 + t;
    int r = idx >> 5, c4 = idx & 31;
    const float4 v = *(const float4*)(h + (size_t)(i0 + r) * DDIM + c4 * 4);
    int c = c4 * 4;
    tile[c + 0][r] = f2h(v.x);
    tile[c + 1][r] = f2h(v.y);
    tile[c + 2][r] = f2h(v.z);
    tile[c + 3][r] = f2h(v.w);
  }
  __syncthreads();
#pragma unroll
  for (int rep = 0; rep < 4; ++rep) {
    int idx = rep * 256 + t;
    int d = idx >> 3, io = (idx & 7) * 8;
    uint4 o;
    o.x = (unsigned)tile[d][io + 0] | ((unsigned)tile[d][io + 1] << 16);
    o.y = (unsigned)tile[d][io + 2] | ((unsigned)tile[d][io + 3] << 16);
    o.z = (unsigned)tile[d][io + 4] | ((unsigned)tile[d][io + 5] << 16);
    o.w = (unsigned)tile[d][io + 6] | ((unsigned)tile[d][io + 7] << 16);
    *(uint4*)(ht + (size_t)d * NROW + i0 + io) = o;
  }
}

// ---------------- fused: EXACT R8 (246.8us best) ----------------
__global__ __launch_bounds__(256, 2) void fused(const float* __restrict__ adj,
                                                const unsigned short* __restrict__ ht,
                                                float* __restrict__ out) {
  __shared__ __align__(16) char smem[40960];
  const int t = threadIdx.x;
  const size_t m0 = (size_t)blockIdx.x * 32;

  const int srow = t >> 3;
  const int chk = (t & 7) ^ (srow & 7);
  const float* ap = adj + (m0 + srow) * (size_t)NROW + chk * 8;
  const unsigned short* hp = ht + (size_t)srow * NROW + chk * 8;

  const int l = t & 63, w = t >> 6;
  const int wr = w >> 1, wc = w & 1;
  const int lr = l & 15, kg = l >> 4;
  const int arow = wr * 16 + lr;
  const int aoff0 = arow * 128 + (((kg    ) ^ (arow & 7)) << 4);
  const int aoff1 = arow * 128 + (((kg + 4) ^ (arow & 7)) << 4);
  const int d0 = wc * 64 + lr;
  const int boff0 = d0 * 128 + (((kg    ) ^ (lr & 7)) << 4);
  const int boff1 = d0 * 128 + (((kg + 4) ^ (lr & 7)) << 4);

  f32x4 acc[4];
#pragma unroll
  for (int cf = 0; cf < 4; ++cf) acc[cf] = (f32x4){0.f, 0.f, 0.f, 0.f};
  f32x4 rsum = (f32x4){0.f, 0.f, 0.f, 0.f};

  f16x8 ones;
#pragma unroll
  for (int e = 0; e < 8; ++e) ones[e] = (_Float16)1.0f;

  float4 pa0 = *(const float4*)(ap);
  float4 pa1 = *(const float4*)(ap + 4);
  uint4 pb0 = *(const uint4*)(hp);
  uint4 pb1 = *(const uint4*)(hp + 32 * NROW);
  uint4 pb2 = *(const uint4*)(hp + 64 * NROW);
  uint4 pb3 = *(const uint4*)(hp + 96 * NROW);

  for (int it = 0; it < NROW / 64; ++it) {
    const int cur = it & 1;

    uint4* bb = (uint4*)(smem + 8192 + cur * 16384);
    bb[t] = pb0; bb[t + 256] = pb1; bb[t + 512] = pb2; bb[t + 768] = pb3;

    const float4 a0 = pa0, a1 = pa1;
    if (it + 1 < NROW / 64) {
      const unsigned short* hb = hp + (it + 1) * 64;
      pb0 = *(const uint4*)(hb);
      pb1 = *(const uint4*)(hb + 32 * NROW);
      pb2 = *(const uint4*)(hb + 64 * NROW);
      pb3 = *(const uint4*)(hb + 96 * NROW);
    }

    uint4 aw;
    aw.x = pkrtz(__expf(a0.x), __expf(a0.y));
    aw.y = pkrtz(__expf(a0.z), __expf(a0.w));
    aw.z = pkrtz(__expf(a1.x), __expf(a1.y));
    aw.w = pkrtz(__expf(a1.z), __expf(a1.w));

    *(uint4*)(smem + cur * 4096 + t * 16) = aw;
    if (it + 1 < NROW / 64) {
      const float* a = ap + (it + 1) * 64;
      pa0 = *(const float4*)(a);
      pa1 = *(const float4*)(a + 4);
    }

    block_sync();

    const char* aB = smem + cur * 4096;
    const char* bB = smem + 8192 + cur * 16384;
    __builtin_amdgcn_s_setprio(1);
    f16x8 af0 = *(const f16x8*)(aB + aoff0);
    f16x8 af1 = *(const f16x8*)(aB + aoff1);
    rsum = __builtin_amdgcn_mfma_f32_16x16x32_f16(af0, ones, rsum, 0, 0, 0);
#pragma unroll
    for (int cf = 0; cf < 4; ++cf) {
      f16x8 bf0 = *(const f16x8*)(bB + boff0 + cf * 2048);
      acc[cf] = __builtin_amdgcn_mfma_f32_16x16x32_f16(af0, bf0, acc[cf], 0, 0, 0);
    }
    rsum = __builtin_amdgcn_mfma_f32_16x16x32_f16(af1, ones, rsum, 0, 0, 0);
#pragma unroll
    for (int cf = 0; cf < 4; ++cf) {
      f16x8 bf1 = *(const f16x8*)(bB + boff1 + cf * 2048);
      acc[cf] = __builtin_amdgcn_mfma_f32_16x16x32_f16(af1, bf1, acc[cf], 0, 0, 0);
    }
    __builtin_amdgcn_s_setprio(0);
  }

#pragma unroll
  for (int r = 0; r < 4; ++r) {
    const int row_l = wr * 16 + kg * 4 + r;
    const float inv = 1.0f / rsum[r];
    float* orow = out + (m0 + row_l) * (size_t)DDIM + wc * 64 + lr;
#pragma unroll
    for (int cf = 0; cf < 4; ++cf) {
      orow[cf * 16] = acc[cf][r] * inv;
    }
  }
}

// ---------------- probe A: R8's exact stripe pattern, 5 x 1GB ----------------
// 512 blocks x 32-row stripes; per step each thread reads 2 float4 at the
// same chk-swizzled offsets R8 uses. Measures this PATTERN's max HBM rate.
__global__ __launch_bounds__(256) void probe_stripe(const float* __restrict__ adj,
                                                    float* __restrict__ sink) {
  const int t = threadIdx.x;
  const int srow = t >> 3;
  const int chk = (t & 7) ^ (srow & 7);
  const float* ap = adj + ((size_t)blockIdx.x * 32 + srow) * (size_t)NROW + chk * 8;
  float s = 0.f;
  for (int rep = 0; rep < 5; ++rep) {
    for (int it = 0; it < 256; ++it) {
      const f32x4 a0 = *(const f32x4*)(ap + it * 64);
      const f32x4 a1 = *(const f32x4*)(ap + it * 64 + 4);
      s += ((a0[0] + a0[1]) + (a0[2] + a0[3])) + ((a1[0] + a1[1]) + (a1[2] + a1[3]));
    }
    asm volatile("" : "+v"(s));  // keep passes live & ordered
  }
  sink[blockIdx.x * 256 + t] = s;
}

// ---------------- probe B: linear contiguous reference, 5 x 1GB ----------------
// Each block reads a contiguous 2MB region per pass (1KB per wave-instr).
__global__ __launch_bounds__(256) void probe_linear(const float* __restrict__ adj,
                                                    float* __restrict__ sink) {
  const int t = threadIdx.x;
  const float* base = adj + (size_t)blockIdx.x * ((size_t)NROW * NROW / 512) + t * 8;
  float s = 0.f;
  for (int rep = 0; rep < 5; ++rep) {
    for (int it = 0; it < 256; ++it) {
      const f32x4 a0 = *(const f32x4*)(base + it * 2048);
      const f32x4 a1 = *(const f32x4*)(base + it * 2048 + 4);
      s += ((a0[0] + a0[1]) + (a0[2] + a0[3])) + ((a1[0] + a1[1]) + (a1[2] + a1[3]));
    }
    asm volatile("" : "+v"(s));
  }
  sink[131072 + blockIdx.x * 256 + t] = s;
}

extern "C" void kernel_launch(void* const* d_in, const int* in_sizes, int n_in,
                              void* d_out, int out_size, void* d_ws, size_t ws_size,
                              hipStream_t stream) {
  (void)in_sizes; (void)n_in; (void)out_size; (void)ws_size;
  const float* h   = (const float*)d_in[0];
  const float* adj = (const float*)d_in[1];
  float* out = (float*)d_out;
  char* ws = (char*)d_ws;
  unsigned short* ht = (unsigned short*)ws;                 // 4 MB
  float* sink = (float*)(ws + (size_t)4 * 1024 * 1024);     // 2 x 512 KB

  prep_ht<<<dim3(NROW / 64), dim3(256), 0, stream>>>(h, ht);
  fused<<<dim3(NROW / 32), dim3(256), 0, stream>>>(adj, ht, out);
  probe_stripe<<<dim3(512), dim3(256), 0, stream>>>(adj, sink);
  probe_linear<<<dim3(512), dim3(256), 0, stream>>>(adj, sink);
}